// Round 2
// baseline (841.648 us; speedup 1.0000x reference)
//
#include <hip/hip_runtime.h>
#include <stdint.h>

#define HID 128
#define EDIM 32

typedef __attribute__((ext_vector_type(8))) short bf16x8;
typedef __attribute__((ext_vector_type(4))) float f4_t;

static __device__ __forceinline__ unsigned short f2bf(float f) {
  union { float f; unsigned int u; } v; v.f = f;
  return (unsigned short)((v.u + 0x7fffu + ((v.u >> 16) & 1u)) >> 16);
}

static __device__ __forceinline__ void atomAddF(float* p, float v) {
#if defined(__gfx950__) || defined(__gfx942__) || defined(__gfx90a__)
  unsafeAtomicAdd(p, v);
#else
  atomicAdd(p, v);
#endif
}

// ---------------------------------------------------------------------------
// Sort pipeline: counting sort of edges by dst.
// ---------------------------------------------------------------------------
__global__ __launch_bounds__(256) void hist_kernel(const int* __restrict__ ei,
                                                   unsigned int* __restrict__ counts,
                                                   int nE) {
  int i = blockIdx.x * blockDim.x + threadIdx.x;
  const int stride = gridDim.x * blockDim.x;
  for (; i < nE; i += stride) atomicAdd(&counts[ei[nE + i]], 1u);
}

// Single-block exclusive scan of counts[N] -> offsets[N+1]
__global__ __launch_bounds__(1024) void scan_kernel(const unsigned int* __restrict__ counts,
                                                    unsigned int* __restrict__ offsets, int N) {
  __shared__ unsigned int wsum[16];
  __shared__ unsigned int carrySh;
  const int tid = threadIdx.x;
  const int lane = tid & 63;
  const int w = tid >> 6;
  if (tid == 0) carrySh = 0;
  __syncthreads();
  for (int base = 0; base < N; base += 1024) {
    const int i = base + tid;
    unsigned int v = (i < N) ? counts[i] : 0u;
    unsigned int s = v;
#pragma unroll
    for (int d = 1; d < 64; d <<= 1) {
      unsigned int t = (unsigned int)__shfl_up((int)s, d);
      if (lane >= d) s += t;
    }
    if (lane == 63) wsum[w] = s;
    __syncthreads();
    if (w == 0 && lane < 16) {
      unsigned int ws_ = wsum[lane];
#pragma unroll
      for (int d = 1; d < 16; d <<= 1) {
        unsigned int t = (unsigned int)__shfl_up((int)ws_, d);
        if (lane >= d) ws_ += t;
      }
      wsum[lane] = ws_;
    }
    __syncthreads();
    const unsigned int waveOff = (w == 0) ? 0u : wsum[w - 1];
    const unsigned int excl = carrySh + waveOff + (s - v);
    if (i < N) offsets[i] = excl;
    const unsigned int chunkTot = wsum[15];
    __syncthreads();
    if (tid == 0) carrySh += chunkTot;
    __syncthreads();
  }
  if (tid == 0) offsets[N] = carrySh;
}

__global__ __launch_bounds__(256) void scatter_kernel(const int* __restrict__ ei,
                                                      const unsigned int* __restrict__ offsets,
                                                      unsigned int* __restrict__ cursors,
                                                      unsigned int* __restrict__ sortedEid,
                                                      int nE) {
  int i = blockIdx.x * blockDim.x + threadIdx.x;
  const int stride = gridDim.x * blockDim.x;
  for (; i < nE; i += stride) {
    const int d = ei[nE + i];
    const unsigned int pos = offsets[d] + atomicAdd(&cursors[d], 1u);
    sortedEid[pos] = (unsigned int)i;
  }
}

// ---------------------------------------------------------------------------
// Aggregation: one wave per node. Per 16-edge step: gather ea rows, one MFMA
// per 16-channel slice (bias in C), epilogue gathers x[src], relu, accumulates
// in registers. Cross-lq shfl reduce, then plain store h = agg + x -> d_out.
// No atomics.
// ---------------------------------------------------------------------------
__global__ __launch_bounds__(256) void agg_kernel(
    const float* __restrict__ x, const int* __restrict__ ei,
    const float* __restrict__ ea, const float* __restrict__ W,
    const float* __restrict__ bias, const unsigned int* __restrict__ offsets,
    const unsigned int* __restrict__ sortedEid, float* __restrict__ h,
    int nNodes, int nE) {
  const int lane = threadIdx.x & 63;
  const int l15 = lane & 15;
  const int lq  = lane >> 4;

  // B fragments in registers: lane holds W[8*lq+j][16*nt+l15], j=0..7
  bf16x8 Wf[8];
  float bv[8];
#pragma unroll
  for (int nt = 0; nt < 8; ++nt) {
#pragma unroll
    for (int j = 0; j < 8; ++j)
      Wf[nt][j] = (short)f2bf(W[(8 * lq + j) * HID + 16 * nt + l15]);
    bv[nt] = bias[16 * nt + l15];
  }

  const int wavesPerBlk = blockDim.x >> 6;
  int waveId = blockIdx.x * wavesPerBlk + ((int)threadIdx.x >> 6);
  const int nWaves = gridDim.x * wavesPerBlk;

  for (int n = waveId; n < nNodes; n += nWaves) {
    const unsigned int beg = offsets[n];
    const unsigned int end = offsets[n + 1];

    float accv[8] = {0, 0, 0, 0, 0, 0, 0, 0};

    for (unsigned int base = beg; base < end; base += 16) {
      // A fragment: row l15 = edge slot base+l15, k = 8*lq+j
      bf16x8 af = {0, 0, 0, 0, 0, 0, 0, 0};
      const unsigned int slotA = base + (unsigned int)l15;
      if (slotA < end) {
        const unsigned int eidA = sortedEid[slotA];
        const float* ap = ea + (size_t)eidA * EDIM + 8 * lq;
        f4_t a0 = *(const f4_t*)ap;
        f4_t a1 = *(const f4_t*)(ap + 4);
#pragma unroll
        for (int j = 0; j < 4; ++j) { af[j] = (short)f2bf(a0[j]); af[j + 4] = (short)f2bf(a1[j]); }
      }

      f4_t acc[8];
#pragma unroll
      for (int nt = 0; nt < 8; ++nt) {
        f4_t c; c[0] = bv[nt]; c[1] = bv[nt]; c[2] = bv[nt]; c[3] = bv[nt];
        acc[nt] = __builtin_amdgcn_mfma_f32_16x16x32_bf16(af, Wf[nt], c, 0, 0, 0);
      }

      // Epilogue: lane owns edge slot base + lq*4 + r, channel l15+16*nt
#pragma unroll
      for (int r = 0; r < 4; ++r) {
        const unsigned int slot = base + (unsigned int)(lq * 4 + r);
        if (slot < end) {
          const unsigned int eid = sortedEid[slot];
          const int s = ei[eid];
          const float* xp = x + (size_t)s * HID + l15;
#pragma unroll
          for (int nt = 0; nt < 8; ++nt)
            accv[nt] += fmaxf(acc[nt][r] + xp[nt * 16], 0.f);
        }
      }
    }

    // reduce across the 4 lane-groups (lanes with equal l15 share channels)
#pragma unroll
    for (int nt = 0; nt < 8; ++nt) {
      accv[nt] += __shfl_xor(accv[nt], 16);
      accv[nt] += __shfl_xor(accv[nt], 32);
    }

    // h = agg + x ; lane stores channels 32*lq+l15 and 32*lq+16+l15
    const int c0 = 32 * lq + l15;
    const size_t rowOff = (size_t)n * HID;
    h[rowOff + c0]      = accv[2 * lq]     + x[rowOff + c0];
    h[rowOff + c0 + 16] = accv[2 * lq + 1] + x[rowOff + c0 + 16];
  }
}

// ---------------------------------------------------------------------------
// Node pass (in place on d_out): h1 = relu(h@W1+b1) ; h2 = h1@W2+b2
// plus per-column sum / sumsq accumulation for GraphNorm.
// ---------------------------------------------------------------------------
__global__ __launch_bounds__(256) void node_kernel(
    float* __restrict__ h, const float* __restrict__ W1, const float* __restrict__ b1,
    const float* __restrict__ W2, const float* __restrict__ b2,
    float* __restrict__ stats, int nNodes, int nTiles) {
  __shared__ unsigned short sW1[128 * 128];
  __shared__ unsigned short sW2[128 * 128];
  __shared__ unsigned short sH1[4][16 * 128];

  for (int idx = threadIdx.x; idx < 128 * 128; idx += 256) {
    int n = idx & 127, k = idx >> 7;
    int off = n * 128 + ((((k >> 3) ^ (n & 15))) << 3) + (k & 7);
    sW1[off] = f2bf(W1[k * HID + n]);
    sW2[off] = f2bf(W2[k * HID + n]);
  }
  __syncthreads();

  const int lane = threadIdx.x & 63;
  const int l15 = lane & 15, lq = lane >> 4;
  const int wv = threadIdx.x >> 6;
  unsigned short* hb = &sH1[wv][0];

  float b1v[8], b2v[8];
#pragma unroll
  for (int nt = 0; nt < 8; ++nt) { b1v[nt] = b1[nt * 16 + l15]; b2v[nt] = b2[nt * 16 + l15]; }
  float ssum[8] = {0, 0, 0, 0, 0, 0, 0, 0};
  float ssq[8]  = {0, 0, 0, 0, 0, 0, 0, 0};

  int waveId = blockIdx.x * 4 + wv;
  const int nWaves = gridDim.x * 4;

  for (int tile = waveId; tile < nTiles; tile += nWaves) {
    const int r0 = tile << 4;
    int rr = r0 + l15; if (rr >= nNodes) rr = nNodes - 1;
    const float* hp = h + (size_t)rr * HID;

    bf16x8 af[4];
#pragma unroll
    for (int kt = 0; kt < 4; ++kt) {
      const int k0 = kt * 32 + 8 * lq;
      f4_t u0 = *(const f4_t*)(hp + k0);
      f4_t u1 = *(const f4_t*)(hp + k0 + 4);
#pragma unroll
      for (int j = 0; j < 4; ++j) {
        af[kt][j]     = (short)f2bf(u0[j]);
        af[kt][j + 4] = (short)f2bf(u1[j]);
      }
    }

    // GEMM1
    f4_t acc[8];
#pragma unroll
    for (int nt = 0; nt < 8; ++nt) {
      f4_t c; c[0] = b1v[nt]; c[1] = b1v[nt]; c[2] = b1v[nt]; c[3] = b1v[nt];
#pragma unroll
      for (int kt = 0; kt < 4; ++kt) {
        bf16x8 wf = *(const bf16x8*)&sW1[(nt * 16 + l15) * 128 + ((((kt * 4 + lq) ^ l15)) << 3)];
        c = __builtin_amdgcn_mfma_f32_16x16x32_bf16(af[kt], wf, c, 0, 0, 0);
      }
      acc[nt] = c;
    }

    // relu(h1) -> per-wave LDS (swizzled row-major [16][128] bf16)
#pragma unroll
    for (int nt = 0; nt < 8; ++nt) {
      const int ghi = 2 * nt + (l15 >> 3);
#pragma unroll
      for (int r = 0; r < 4; ++r) {
        const int row = lq * 4 + r;
        hb[row * 128 + ((ghi ^ (row & 15)) << 3) + (l15 & 7)] = f2bf(fmaxf(acc[nt][r], 0.f));
      }
    }
    asm volatile("s_waitcnt lgkmcnt(0)" ::: "memory");
    __builtin_amdgcn_sched_barrier(0);

    bf16x8 af2[4];
#pragma unroll
    for (int kt = 0; kt < 4; ++kt)
      af2[kt] = *(const bf16x8*)&hb[l15 * 128 + ((((kt * 4 + lq) ^ l15)) << 3)];

    // GEMM2
    f4_t acc2[8];
#pragma unroll
    for (int nt = 0; nt < 8; ++nt) {
      f4_t c; c[0] = b2v[nt]; c[1] = b2v[nt]; c[2] = b2v[nt]; c[3] = b2v[nt];
#pragma unroll
      for (int kt = 0; kt < 4; ++kt) {
        bf16x8 wf = *(const bf16x8*)&sW2[(nt * 16 + l15) * 128 + ((((kt * 4 + lq) ^ l15)) << 3)];
        c = __builtin_amdgcn_mfma_f32_16x16x32_bf16(af2[kt], wf, c, 0, 0, 0);
      }
      acc2[nt] = c;
    }

    // write h2 (in place) + accumulate stats
#pragma unroll
    for (int nt = 0; nt < 8; ++nt) {
#pragma unroll
      for (int r = 0; r < 4; ++r) {
        const int row = r0 + lq * 4 + r;
        if (row < nNodes) {
          float v = acc2[nt][r];
          h[(size_t)row * HID + nt * 16 + l15] = v;
          ssum[nt] += v; ssq[nt] += v * v;
        }
      }
    }
  }

#pragma unroll
  for (int nt = 0; nt < 8; ++nt) {
    float a = ssum[nt], b = ssq[nt];
    a += __shfl_xor(a, 16); b += __shfl_xor(b, 16);
    a += __shfl_xor(a, 32); b += __shfl_xor(b, 32);
    if (lq == 0) {
      atomAddF(&stats[nt * 16 + l15], a);
      atomAddF(&stats[HID + nt * 16 + l15], b);
    }
  }
}

// ---------------------------------------------------------------------------
// Fold GraphNorm into per-column affine: out = relu(A*h2 + B)
// var = E[(h - s*m)^2] = msq - (2s - s^2) m^2
// ---------------------------------------------------------------------------
__global__ void norm_prep(float* __restrict__ stats, const float* __restrict__ gw,
                          const float* __restrict__ gb, const float* __restrict__ gs,
                          int nNodes) {
  int c = threadIdx.x;
  if (c < HID) {
    float invN = 1.f / (float)nNodes;
    float m   = stats[c] * invN;
    float msq = stats[HID + c] * invN;
    float s   = gs[c];
    float var = msq - (2.f * s - s * s) * m * m;
    float A = gw[c] * rsqrtf(var + 1e-5f);
    float B = gb[c] - A * s * m;
    stats[2 * HID + c] = A;
    stats[3 * HID + c] = B;
  }
}

__global__ __launch_bounds__(256) void norm_kernel(const float* __restrict__ stats,
                                                   float* __restrict__ out, int total4) {
  const f4_t* A4 = (const f4_t*)(stats + 2 * HID);
  const f4_t* B4 = (const f4_t*)(stats + 3 * HID);
  int i = blockIdx.x * blockDim.x + threadIdx.x;
  const int stride = gridDim.x * blockDim.x;
  for (; i < total4; i += stride) {
    const int cg = i & 31;
    f4_t h = ((const f4_t*)out)[i];
    f4_t a = A4[cg], b = B4[cg];
    f4_t o;
#pragma unroll
    for (int j = 0; j < 4; ++j) o[j] = fmaxf(fmaf(h[j], a[j], b[j]), 0.f);
    ((f4_t*)out)[i] = o;
  }
}

extern "C" void kernel_launch(void* const* d_in, const int* in_sizes, int n_in,
                              void* d_out, int out_size, void* d_ws, size_t ws_size,
                              hipStream_t stream) {
  const float* x  = (const float*)d_in[0];
  const int*   ei = (const int*)d_in[1];
  const float* ea = (const float*)d_in[2];
  const float* eW = (const float*)d_in[3];
  const float* eb = (const float*)d_in[4];
  const float* W1 = (const float*)d_in[5];
  const float* b1 = (const float*)d_in[6];
  const float* W2 = (const float*)d_in[7];
  const float* b2 = (const float*)d_in[8];
  const float* gw = (const float*)d_in[9];
  const float* gb = (const float*)d_in[10];
  const float* gs = (const float*)d_in[11];
  float* out = (float*)d_out;

  const int nNodes = in_sizes[0] / HID;   // 100000
  const int nE     = in_sizes[1] / 2;     // 1600000

  // ws layout: [stats 2KB][counts 400000][cursors 400000][offsets 400064][sortedEid]
  char* w = (char*)d_ws;
  float* stats          = (float*)w;                      // 4*HID floats
  unsigned int* counts  = (unsigned int*)(w + 2048);
  unsigned int* cursors = (unsigned int*)(w + 2048 + 400000);
  unsigned int* offsets = (unsigned int*)(w + 2048 + 800000);
  unsigned int* sortedEid = (unsigned int*)(w + 2048 + 800000 + 400064);

  // zero stats + counts + cursors (one contiguous range)
  hipMemsetAsync(d_ws, 0, 2048 + 800000, stream);

  hist_kernel<<<1024, 256, 0, stream>>>(ei, counts, nE);
  scan_kernel<<<1, 1024, 0, stream>>>(counts, offsets, nNodes);
  scatter_kernel<<<1024, 256, 0, stream>>>(ei, offsets, cursors, sortedEid, nE);

  agg_kernel<<<2048, 256, 0, stream>>>(x, ei, ea, eW, eb, offsets, sortedEid, out, nNodes, nE);

  const int nTiles = (nNodes + 15) >> 4;
  node_kernel<<<782, 256, 0, stream>>>(out, W1, b1, W2, b2, stats, nNodes, nTiles);

  norm_prep<<<1, 128, 0, stream>>>(stats, gw, gb, gs, nNodes);
  norm_kernel<<<2048, 256, 0, stream>>>(stats, out, nNodes * (HID / 4));
}

// Round 3
// 624.675 us; speedup vs baseline: 1.3473x; 1.3473x over previous
//
#include <hip/hip_runtime.h>
#include <stdint.h>

#define HID 128
#define EDIM 32

typedef __attribute__((ext_vector_type(8))) short bf16x8;
typedef __attribute__((ext_vector_type(4))) float f4_t;

static __device__ __forceinline__ unsigned short f2bf(float f) {
  union { float f; unsigned int u; } v; v.f = f;
  return (unsigned short)((v.u + 0x7fffu + ((v.u >> 16) & 1u)) >> 16);
}

static __device__ __forceinline__ void atomAddF(float* p, float v) {
#if defined(__gfx950__) || defined(__gfx942__) || defined(__gfx90a__)
  unsafeAtomicAdd(p, v);
#else
  atomicAdd(p, v);
#endif
}

// ---------------------------------------------------------------------------
// Pass 1: histogram of dst + (optional) ea f32 -> bf16 conversion (sequential,
// non-temporal reads so the stream does not pollute L2/L3 ahead of agg).
// ---------------------------------------------------------------------------
__global__ __launch_bounds__(256) void hist_conv(const int* __restrict__ ei,
                                                 const float* __restrict__ ea,
                                                 unsigned int* __restrict__ counts,
                                                 unsigned short* __restrict__ eaBf,
                                                 int nE, int doConv) {
  int tid = blockIdx.x * blockDim.x + threadIdx.x;
  const int stride = gridDim.x * blockDim.x;
  for (int i = tid; i < nE; i += stride) atomicAdd(&counts[ei[nE + i]], 1u);
  if (doConv) {
    const int nCh = nE * 4;  // 8 floats per chunk
    for (int j = tid; j < nCh; j += stride) {
      const f4_t* p = (const f4_t*)(ea + (size_t)j * 8);
      f4_t a0 = __builtin_nontemporal_load(p);
      f4_t a1 = __builtin_nontemporal_load(p + 1);
      bf16x8 o;
#pragma unroll
      for (int k = 0; k < 4; ++k) { o[k] = (short)f2bf(a0[k]); o[k + 4] = (short)f2bf(a1[k]); }
      *(bf16x8*)(eaBf + (size_t)j * 8) = o;
    }
  }
}

// ---------------------------------------------------------------------------
// Chunked exclusive scan of counts[N] -> offsets[N+1]  (3 kernels)
// ---------------------------------------------------------------------------
__global__ __launch_bounds__(1024) void chunk_sum(const unsigned int* __restrict__ counts,
                                                  unsigned int* __restrict__ chunkSum, int N) {
  __shared__ unsigned int wsum[16];
  const int tid = threadIdx.x;
  const int i = blockIdx.x * 1024 + tid;
  unsigned int v = (i < N) ? counts[i] : 0u;
#pragma unroll
  for (int d = 1; d < 64; d <<= 1) v += (unsigned int)__shfl_xor((int)v, d);
  if ((tid & 63) == 0) wsum[tid >> 6] = v;
  __syncthreads();
  if (tid < 16) {
    unsigned int t = wsum[tid];
#pragma unroll
    for (int d = 1; d < 16; d <<= 1) t += (unsigned int)__shfl_xor((int)t, d);
    if (tid == 0) chunkSum[blockIdx.x] = t;
  }
}

__global__ __launch_bounds__(256) void scan_chunks(const unsigned int* __restrict__ chunkSum,
                                                   unsigned int* __restrict__ chunkOff,
                                                   unsigned int* __restrict__ offsets,
                                                   int nChunks, int N) {
  __shared__ unsigned int wsum[4];
  const int tid = threadIdx.x, lane = tid & 63, w = tid >> 6;
  unsigned int v = (tid < nChunks) ? chunkSum[tid] : 0u;
  unsigned int s = v;
#pragma unroll
  for (int d = 1; d < 64; d <<= 1) {
    unsigned int t = (unsigned int)__shfl_up((int)s, d);
    if (lane >= d) s += t;
  }
  if (lane == 63) wsum[w] = s;
  __syncthreads();
  unsigned int wOff = 0;
  for (int k = 0; k < w; ++k) wOff += wsum[k];
  if (tid < nChunks) chunkOff[tid] = wOff + s - v;
  if (tid == nChunks - 1) offsets[N] = wOff + s;
}

__global__ __launch_bounds__(1024) void scan_local(const unsigned int* __restrict__ counts,
                                                   const unsigned int* __restrict__ chunkOff,
                                                   unsigned int* __restrict__ offsets, int N) {
  __shared__ unsigned int wsum[16];
  const int tid = threadIdx.x, lane = tid & 63, w = tid >> 6;
  const int i = blockIdx.x * 1024 + tid;
  unsigned int v = (i < N) ? counts[i] : 0u;
  unsigned int s = v;
#pragma unroll
  for (int d = 1; d < 64; d <<= 1) {
    unsigned int t = (unsigned int)__shfl_up((int)s, d);
    if (lane >= d) s += t;
  }
  if (lane == 63) wsum[w] = s;
  __syncthreads();
  unsigned int wOff = 0;
  for (int k = 0; k < w; ++k) wOff += wsum[k];
  if (i < N) offsets[i] = chunkOff[blockIdx.x] + wOff + (s - v);
}

// ---------------------------------------------------------------------------
// Scatter: counting-sort edge ids by dst; optionally also store src per slot.
// ---------------------------------------------------------------------------
template <bool WRITE_SRC>
__global__ __launch_bounds__(256) void scatter_kernel(const int* __restrict__ ei,
                                                      const unsigned int* __restrict__ offsets,
                                                      unsigned int* __restrict__ cursors,
                                                      unsigned int* __restrict__ sortedEid,
                                                      unsigned int* __restrict__ sortedSrc,
                                                      int nE) {
  int i = blockIdx.x * blockDim.x + threadIdx.x;
  const int stride = gridDim.x * blockDim.x;
  for (; i < nE; i += stride) {
    const int d = ei[nE + i];
    const unsigned int pos = offsets[d] + atomicAdd(&cursors[d], 1u);
    sortedEid[pos] = (unsigned int)i;
    if (WRITE_SRC) sortedSrc[pos] = (unsigned int)ei[i];
  }
}

// ---------------------------------------------------------------------------
// Aggregation: one wave per node, no atomics.
// MODE 0: bf16 ea copy + sortedSrc.  MODE 1: f32 ea + sortedSrc.
// MODE 2: f32 ea + ei[] indirection (minimal workspace).
// ---------------------------------------------------------------------------
template <int MODE>
__global__ __launch_bounds__(256) void agg_kernel(
    const float* __restrict__ x, const int* __restrict__ ei,
    const float* __restrict__ ea, const unsigned short* __restrict__ eaBf,
    const float* __restrict__ W, const float* __restrict__ bias,
    const unsigned int* __restrict__ offsets, const unsigned int* __restrict__ sortedEid,
    const unsigned int* __restrict__ sortedSrc, float* __restrict__ h,
    int nNodes, int nE) {
  const int lane = threadIdx.x & 63;
  const int l15 = lane & 15;
  const int lq  = lane >> 4;

  bf16x8 Wf[8];
  float bv[8];
#pragma unroll
  for (int nt = 0; nt < 8; ++nt) {
#pragma unroll
    for (int j = 0; j < 8; ++j)
      Wf[nt][j] = (short)f2bf(W[(8 * lq + j) * HID + 16 * nt + l15]);
    bv[nt] = bias[16 * nt + l15];
  }

  const int wavesPerBlk = blockDim.x >> 6;
  int waveId = blockIdx.x * wavesPerBlk + ((int)threadIdx.x >> 6);
  const int nWaves = gridDim.x * wavesPerBlk;

  for (int n = waveId; n < nNodes; n += nWaves) {
    const unsigned int beg = offsets[n];
    const unsigned int end = offsets[n + 1];

    float accv[8] = {0, 0, 0, 0, 0, 0, 0, 0};

    for (unsigned int base = beg; base < end; base += 16) {
      bf16x8 af = {0, 0, 0, 0, 0, 0, 0, 0};
      const unsigned int slotA = base + (unsigned int)l15;
      if (slotA < end) {
        const unsigned int eidA = __builtin_nontemporal_load(&sortedEid[slotA]);
        if (MODE == 0) {
          af = __builtin_nontemporal_load((const bf16x8*)(eaBf + (size_t)eidA * EDIM + 8 * lq));
        } else {
          const float* ap = ea + (size_t)eidA * EDIM + 8 * lq;
          f4_t a0 = *(const f4_t*)ap;
          f4_t a1 = *(const f4_t*)(ap + 4);
#pragma unroll
          for (int j = 0; j < 4; ++j) { af[j] = (short)f2bf(a0[j]); af[j + 4] = (short)f2bf(a1[j]); }
        }
      }

      f4_t acc[8];
#pragma unroll
      for (int nt = 0; nt < 8; ++nt) {
        f4_t c; c[0] = bv[nt]; c[1] = bv[nt]; c[2] = bv[nt]; c[3] = bv[nt];
        acc[nt] = __builtin_amdgcn_mfma_f32_16x16x32_bf16(af, Wf[nt], c, 0, 0, 0);
      }

#pragma unroll
      for (int r = 0; r < 4; ++r) {
        const unsigned int slot = base + (unsigned int)(lq * 4 + r);
        if (slot < end) {
          int s;
          if (MODE == 2) {
            const unsigned int eid = __builtin_nontemporal_load(&sortedEid[slot]);
            s = ei[eid];
          } else {
            s = (int)__builtin_nontemporal_load(&sortedSrc[slot]);
          }
          const float* xp = x + (size_t)s * HID + l15;
#pragma unroll
          for (int nt = 0; nt < 8; ++nt)
            accv[nt] += fmaxf(acc[nt][r] + xp[nt * 16], 0.f);
        }
      }
    }

#pragma unroll
    for (int nt = 0; nt < 8; ++nt) {
      accv[nt] += __shfl_xor(accv[nt], 16);
      accv[nt] += __shfl_xor(accv[nt], 32);
    }

    const int c0 = 32 * lq + l15;
    const size_t rowOff = (size_t)n * HID;
    h[rowOff + c0]      = accv[2 * lq]     + x[rowOff + c0];
    h[rowOff + c0 + 16] = accv[2 * lq + 1] + x[rowOff + c0 + 16];
  }
}

// ---------------------------------------------------------------------------
// Node pass (in place on d_out): h1 = relu(h@W1+b1) ; h2 = h1@W2+b2
// plus per-column sum / sumsq accumulation for GraphNorm.
// ---------------------------------------------------------------------------
__global__ __launch_bounds__(256) void node_kernel(
    float* __restrict__ h, const float* __restrict__ W1, const float* __restrict__ b1,
    const float* __restrict__ W2, const float* __restrict__ b2,
    float* __restrict__ stats, int nNodes, int nTiles) {
  __shared__ unsigned short sW1[128 * 128];
  __shared__ unsigned short sW2[128 * 128];
  __shared__ unsigned short sH1[4][16 * 128];

  for (int idx = threadIdx.x; idx < 128 * 128; idx += 256) {
    int n = idx & 127, k = idx >> 7;
    int off = n * 128 + ((((k >> 3) ^ (n & 15))) << 3) + (k & 7);
    sW1[off] = f2bf(W1[k * HID + n]);
    sW2[off] = f2bf(W2[k * HID + n]);
  }
  __syncthreads();

  const int lane = threadIdx.x & 63;
  const int l15 = lane & 15, lq = lane >> 4;
  const int wv = threadIdx.x >> 6;
  unsigned short* hb = &sH1[wv][0];

  float b1v[8], b2v[8];
#pragma unroll
  for (int nt = 0; nt < 8; ++nt) { b1v[nt] = b1[nt * 16 + l15]; b2v[nt] = b2[nt * 16 + l15]; }
  float ssum[8] = {0, 0, 0, 0, 0, 0, 0, 0};
  float ssq[8]  = {0, 0, 0, 0, 0, 0, 0, 0};

  int waveId = blockIdx.x * 4 + wv;
  const int nWaves = gridDim.x * 4;

  for (int tile = waveId; tile < nTiles; tile += nWaves) {
    const int r0 = tile << 4;
    int rr = r0 + l15; if (rr >= nNodes) rr = nNodes - 1;
    const float* hp = h + (size_t)rr * HID;

    bf16x8 af[4];
#pragma unroll
    for (int kt = 0; kt < 4; ++kt) {
      const int k0 = kt * 32 + 8 * lq;
      f4_t u0 = *(const f4_t*)(hp + k0);
      f4_t u1 = *(const f4_t*)(hp + k0 + 4);
#pragma unroll
      for (int j = 0; j < 4; ++j) {
        af[kt][j]     = (short)f2bf(u0[j]);
        af[kt][j + 4] = (short)f2bf(u1[j]);
      }
    }

    f4_t acc[8];
#pragma unroll
    for (int nt = 0; nt < 8; ++nt) {
      f4_t c; c[0] = b1v[nt]; c[1] = b1v[nt]; c[2] = b1v[nt]; c[3] = b1v[nt];
#pragma unroll
      for (int kt = 0; kt < 4; ++kt) {
        bf16x8 wf = *(const bf16x8*)&sW1[(nt * 16 + l15) * 128 + ((((kt * 4 + lq) ^ l15)) << 3)];
        c = __builtin_amdgcn_mfma_f32_16x16x32_bf16(af[kt], wf, c, 0, 0, 0);
      }
      acc[nt] = c;
    }

#pragma unroll
    for (int nt = 0; nt < 8; ++nt) {
      const int ghi = 2 * nt + (l15 >> 3);
#pragma unroll
      for (int r = 0; r < 4; ++r) {
        const int row = lq * 4 + r;
        hb[row * 128 + ((ghi ^ (row & 15)) << 3) + (l15 & 7)] = f2bf(fmaxf(acc[nt][r], 0.f));
      }
    }
    asm volatile("s_waitcnt lgkmcnt(0)" ::: "memory");
    __builtin_amdgcn_sched_barrier(0);

    bf16x8 af2[4];
#pragma unroll
    for (int kt = 0; kt < 4; ++kt)
      af2[kt] = *(const bf16x8*)&hb[l15 * 128 + ((((kt * 4 + lq) ^ l15)) << 3)];

    f4_t acc2[8];
#pragma unroll
    for (int nt = 0; nt < 8; ++nt) {
      f4_t c; c[0] = b2v[nt]; c[1] = b2v[nt]; c[2] = b2v[nt]; c[3] = b2v[nt];
#pragma unroll
      for (int kt = 0; kt < 4; ++kt) {
        bf16x8 wf = *(const bf16x8*)&sW2[(nt * 16 + l15) * 128 + ((((kt * 4 + lq) ^ l15)) << 3)];
        c = __builtin_amdgcn_mfma_f32_16x16x32_bf16(af2[kt], wf, c, 0, 0, 0);
      }
      acc2[nt] = c;
    }

#pragma unroll
    for (int nt = 0; nt < 8; ++nt) {
#pragma unroll
      for (int r = 0; r < 4; ++r) {
        const int row = r0 + lq * 4 + r;
        if (row < nNodes) {
          float v = acc2[nt][r];
          h[(size_t)row * HID + nt * 16 + l15] = v;
          ssum[nt] += v; ssq[nt] += v * v;
        }
      }
    }
  }

#pragma unroll
  for (int nt = 0; nt < 8; ++nt) {
    float a = ssum[nt], b = ssq[nt];
    a += __shfl_xor(a, 16); b += __shfl_xor(b, 16);
    a += __shfl_xor(a, 32); b += __shfl_xor(b, 32);
    if (lq == 0) {
      atomAddF(&stats[nt * 16 + l15], a);
      atomAddF(&stats[HID + nt * 16 + l15], b);
    }
  }
}

__global__ void norm_prep(float* __restrict__ stats, const float* __restrict__ gw,
                          const float* __restrict__ gb, const float* __restrict__ gs,
                          int nNodes) {
  int c = threadIdx.x;
  if (c < HID) {
    float invN = 1.f / (float)nNodes;
    float m   = stats[c] * invN;
    float msq = stats[HID + c] * invN;
    float s   = gs[c];
    float var = msq - (2.f * s - s * s) * m * m;
    float A = gw[c] * rsqrtf(var + 1e-5f);
    float B = gb[c] - A * s * m;
    stats[2 * HID + c] = A;
    stats[3 * HID + c] = B;
  }
}

__global__ __launch_bounds__(256) void norm_kernel(const float* __restrict__ stats,
                                                   float* __restrict__ out, int total4) {
  const f4_t* A4 = (const f4_t*)(stats + 2 * HID);
  const f4_t* B4 = (const f4_t*)(stats + 3 * HID);
  int i = blockIdx.x * blockDim.x + threadIdx.x;
  const int stride = gridDim.x * blockDim.x;
  for (; i < total4; i += stride) {
    const int cg = i & 31;
    f4_t h = ((const f4_t*)out)[i];
    f4_t a = A4[cg], b = B4[cg];
    f4_t o;
#pragma unroll
    for (int j = 0; j < 4; ++j) o[j] = fmaxf(fmaf(h[j], a[j], b[j]), 0.f);
    ((f4_t*)out)[i] = o;
  }
}

extern "C" void kernel_launch(void* const* d_in, const int* in_sizes, int n_in,
                              void* d_out, int out_size, void* d_ws, size_t ws_size,
                              hipStream_t stream) {
  const float* x  = (const float*)d_in[0];
  const int*   ei = (const int*)d_in[1];
  const float* ea = (const float*)d_in[2];
  const float* eW = (const float*)d_in[3];
  const float* eb = (const float*)d_in[4];
  const float* W1 = (const float*)d_in[5];
  const float* b1 = (const float*)d_in[6];
  const float* W2 = (const float*)d_in[7];
  const float* b2 = (const float*)d_in[8];
  const float* gw = (const float*)d_in[9];
  const float* gb = (const float*)d_in[10];
  const float* gs = (const float*)d_in[11];
  float* out = (float*)d_out;

  const int nNodes = in_sizes[0] / HID;   // 100000
  const int nE     = in_sizes[1] / 2;     // 1600000

  // ws layout (64B-aligned fields)
  char* w = (char*)d_ws;
  const size_t offStats   = 0;                               // 4*HID f32
  const size_t offCounts  = 2048;                            // nNodes u32
  const size_t offCursors = offCounts  + 400000;             // nNodes u32
  const size_t offOffsets = offCursors + 400000;             // (nNodes+1) u32
  const size_t offChunk   = offOffsets + 400064;             // chunk sums/offs
  const size_t offSEid    = offChunk   + 2048;               // nE u32
  const size_t offSSrc    = offSEid    + (size_t)nE * 4;     // nE u32
  const size_t offEaBf    = offSSrc    + (size_t)nE * 4;     // nE*EDIM bf16
  const size_t needFull   = offEaBf + (size_t)nE * EDIM * 2;
  const size_t needSrc    = offEaBf;

  float* stats            = (float*)(w + offStats);
  unsigned int* counts    = (unsigned int*)(w + offCounts);
  unsigned int* cursors   = (unsigned int*)(w + offCursors);
  unsigned int* offsets   = (unsigned int*)(w + offOffsets);
  unsigned int* chunkSum  = (unsigned int*)(w + offChunk);
  unsigned int* chunkOff  = (unsigned int*)(w + offChunk + 1024);
  unsigned int* sortedEid = (unsigned int*)(w + offSEid);
  unsigned int* sortedSrc = (unsigned int*)(w + offSSrc);
  unsigned short* eaBf    = (unsigned short*)(w + offEaBf);

  const int mode = (ws_size >= needFull) ? 0 : (ws_size >= needSrc ? 1 : 2);

  hipMemsetAsync(d_ws, 0, offOffsets, stream);  // stats + counts + cursors

  hist_conv<<<2048, 256, 0, stream>>>(ei, ea, counts, eaBf, nE, mode == 0 ? 1 : 0);

  const int nChunks = (nNodes + 1023) / 1024;   // 98
  chunk_sum<<<nChunks, 1024, 0, stream>>>(counts, chunkSum, nNodes);
  scan_chunks<<<1, 256, 0, stream>>>(chunkSum, chunkOff, offsets, nChunks, nNodes);
  scan_local<<<nChunks, 1024, 0, stream>>>(counts, chunkOff, offsets, nNodes);

  if (mode == 2)
    scatter_kernel<false><<<1024, 256, 0, stream>>>(ei, offsets, cursors, sortedEid, sortedSrc, nE);
  else
    scatter_kernel<true><<<1024, 256, 0, stream>>>(ei, offsets, cursors, sortedEid, sortedSrc, nE);

  if (mode == 0)
    agg_kernel<0><<<8192, 256, 0, stream>>>(x, ei, ea, eaBf, eW, eb, offsets, sortedEid, sortedSrc, out, nNodes, nE);
  else if (mode == 1)
    agg_kernel<1><<<8192, 256, 0, stream>>>(x, ei, ea, eaBf, eW, eb, offsets, sortedEid, sortedSrc, out, nNodes, nE);
  else
    agg_kernel<2><<<8192, 256, 0, stream>>>(x, ei, ea, eaBf, eW, eb, offsets, sortedEid, sortedSrc, out, nNodes, nE);

  const int nTiles = (nNodes + 15) >> 4;
  node_kernel<<<782, 256, 0, stream>>>(out, W1, b1, W2, b2, stats, nNodes, nTiles);

  norm_prep<<<1, 128, 0, stream>>>(stats, gw, gb, gs, nNodes);
  norm_kernel<<<2048, 256, 0, stream>>>(stats, out, nNodes * (HID / 4));
}

// Round 4
// 472.234 us; speedup vs baseline: 1.7823x; 1.3228x over previous
//
#include <hip/hip_runtime.h>
#include <stdint.h>

#define HID 128
#define EDIM 32

typedef __attribute__((ext_vector_type(8))) short bf16x8;
typedef __attribute__((ext_vector_type(4))) float f4_t;

static __device__ __forceinline__ unsigned short f2bf(float f) {
  union { float f; unsigned int u; } v; v.f = f;
  return (unsigned short)((v.u + 0x7fffu + ((v.u >> 16) & 1u)) >> 16);
}

static __device__ __forceinline__ float bf2f(short s) {
  union { unsigned int u; float f; } v;
  v.u = ((unsigned int)(unsigned short)s) << 16;
  return v.f;
}

static __device__ __forceinline__ void atomAddF(float* p, float v) {
#if defined(__gfx950__) || defined(__gfx942__) || defined(__gfx90a__)
  unsafeAtomicAdd(p, v);
#else
  atomicAdd(p, v);
#endif
}

// ---------------------------------------------------------------------------
// Pass 1: histogram of dst + (mode 0) build x_perm: bf16, permuted so that
// lane l15's epilogue channels (l15 + 16*nt, nt=0..7) are contiguous:
//   x_perm[node][ (c&15)*8 + (c>>4) ] = bf16(x[node][c])
// ---------------------------------------------------------------------------
__global__ __launch_bounds__(256) void hist_xperm(const int* __restrict__ ei,
                                                  const float* __restrict__ x,
                                                  unsigned int* __restrict__ counts,
                                                  unsigned short* __restrict__ xPerm,
                                                  int nE, int nNodes, int doPerm) {
  int tid = blockIdx.x * blockDim.x + threadIdx.x;
  const int stride = gridDim.x * blockDim.x;
  for (int i = tid; i < nE; i += stride) atomicAdd(&counts[ei[nE + i]], 1u);
  if (doPerm) {
    const int nCh = nNodes * 16;  // chunk = 8 output bf16
    for (int j = tid; j < nCh; j += stride) {
      const int node = j >> 4, g = j & 15;
      const float* xp = x + (size_t)node * HID + g;
      bf16x8 o;
#pragma unroll
      for (int k = 0; k < 8; ++k) o[k] = (short)f2bf(xp[k * 16]);
      *(bf16x8*)(xPerm + (size_t)node * HID + g * 8) = o;
    }
  }
}

// ---------------------------------------------------------------------------
// Chunked exclusive scan of counts[N] -> offsets[N+1]; also fills cursors.
// ---------------------------------------------------------------------------
__global__ __launch_bounds__(1024) void chunk_sum(const unsigned int* __restrict__ counts,
                                                  unsigned int* __restrict__ chunkSum, int N) {
  __shared__ unsigned int wsum[16];
  const int tid = threadIdx.x;
  const int i = blockIdx.x * 1024 + tid;
  unsigned int v = (i < N) ? counts[i] : 0u;
#pragma unroll
  for (int d = 1; d < 64; d <<= 1) v += (unsigned int)__shfl_xor((int)v, d);
  if ((tid & 63) == 0) wsum[tid >> 6] = v;
  __syncthreads();
  if (tid < 16) {
    unsigned int t = wsum[tid];
#pragma unroll
    for (int d = 1; d < 16; d <<= 1) t += (unsigned int)__shfl_xor((int)t, d);
    if (tid == 0) chunkSum[blockIdx.x] = t;
  }
}

__global__ __launch_bounds__(256) void scan_chunks(const unsigned int* __restrict__ chunkSum,
                                                   unsigned int* __restrict__ chunkOff,
                                                   unsigned int* __restrict__ offsets,
                                                   int nChunks, int N) {
  __shared__ unsigned int wsum[4];
  const int tid = threadIdx.x, lane = tid & 63, w = tid >> 6;
  unsigned int v = (tid < nChunks) ? chunkSum[tid] : 0u;
  unsigned int s = v;
#pragma unroll
  for (int d = 1; d < 64; d <<= 1) {
    unsigned int t = (unsigned int)__shfl_up((int)s, d);
    if (lane >= d) s += t;
  }
  if (lane == 63) wsum[w] = s;
  __syncthreads();
  unsigned int wOff = 0;
  for (int k = 0; k < w; ++k) wOff += wsum[k];
  if (tid < nChunks) chunkOff[tid] = wOff + s - v;
  if (tid == nChunks - 1) offsets[N] = wOff + s;
}

__global__ __launch_bounds__(1024) void scan_local(const unsigned int* __restrict__ counts,
                                                   const unsigned int* __restrict__ chunkOff,
                                                   unsigned int* __restrict__ offsets,
                                                   unsigned int* __restrict__ cursors, int N) {
  __shared__ unsigned int wsum[16];
  const int tid = threadIdx.x, lane = tid & 63, w = tid >> 6;
  const int i = blockIdx.x * 1024 + tid;
  unsigned int v = (i < N) ? counts[i] : 0u;
  unsigned int s = v;
#pragma unroll
  for (int d = 1; d < 64; d <<= 1) {
    unsigned int t = (unsigned int)__shfl_up((int)s, d);
    if (lane >= d) s += t;
  }
  if (lane == 63) wsum[w] = s;
  __syncthreads();
  unsigned int wOff = 0;
  for (int k = 0; k < w; ++k) wOff += wsum[k];
  if (i < N) {
    const unsigned int ex = chunkOff[blockIdx.x] + wOff + (s - v);
    offsets[i] = ex;
    cursors[i] = ex;
  }
}

// ---------------------------------------------------------------------------
// Fused scatter + ea convert (modes 0/1): 4 lanes per edge. Computes the
// edge's sorted position (atomic on cursors = absolute pos), writes
// sortedSrc[pos] and eaSorted[pos] (bf16 row, 64 B contiguous random write).
// Reads of ea are fully coalesced streams.
// ---------------------------------------------------------------------------
__global__ __launch_bounds__(256) void scatter_conv(const int* __restrict__ ei,
                                                    const float* __restrict__ ea,
                                                    unsigned int* __restrict__ cursors,
                                                    unsigned int* __restrict__ sortedSrc,
                                                    unsigned short* __restrict__ eaSorted,
                                                    int nE) {
  const int lane = threadIdx.x & 63;
  const int q = lane & 3;
  int t = blockIdx.x * blockDim.x + threadIdx.x;
  const int eStride = (gridDim.x * blockDim.x) >> 2;
  for (int e = t >> 2; e < nE; e += eStride) {
    unsigned int pos = 0;
    if (q == 0) {
      const int d = ei[nE + e];
      pos = atomicAdd(&cursors[d], 1u);
      sortedSrc[pos] = (unsigned int)ei[e];
    }
    pos = (unsigned int)__shfl((int)pos, lane & ~3);
    const f4_t* ap = (const f4_t*)(ea + (size_t)e * EDIM + q * 8);
    f4_t a0 = __builtin_nontemporal_load(ap);
    f4_t a1 = __builtin_nontemporal_load(ap + 1);
    bf16x8 o;
#pragma unroll
    for (int k = 0; k < 4; ++k) { o[k] = (short)f2bf(a0[k]); o[k + 4] = (short)f2bf(a1[k]); }
    *(bf16x8*)(eaSorted + (size_t)pos * EDIM + q * 8) = o;
  }
}

// Mode 2 fallback: plain scatter of eid + src (minimal workspace).
__global__ __launch_bounds__(256) void scatter_min(const int* __restrict__ ei,
                                                   unsigned int* __restrict__ cursors,
                                                   unsigned int* __restrict__ sortedEid,
                                                   unsigned int* __restrict__ sortedSrc,
                                                   int nE) {
  int i = blockIdx.x * blockDim.x + threadIdx.x;
  const int stride = gridDim.x * blockDim.x;
  for (; i < nE; i += stride) {
    const int d = ei[nE + i];
    const unsigned int pos = atomicAdd(&cursors[d], 1u);
    sortedEid[pos] = (unsigned int)i;
    sortedSrc[pos] = (unsigned int)ei[i];
  }
}

// ---------------------------------------------------------------------------
// Aggregation: one wave per node, no atomics.
// MODE 0: eaSorted stream + x_perm bf16 gathers (1x16B per edge per lane).
// MODE 1: eaSorted stream + f32 x scalar gathers.
// MODE 2: f32 ea gather via sortedEid + f32 x scalar gathers.
// ---------------------------------------------------------------------------
template <int MODE>
__global__ __launch_bounds__(256) void agg_kernel(
    const float* __restrict__ x, const unsigned short* __restrict__ xPerm,
    const float* __restrict__ ea, const unsigned short* __restrict__ eaSorted,
    const float* __restrict__ W, const float* __restrict__ bias,
    const unsigned int* __restrict__ offsets, const unsigned int* __restrict__ sortedEid,
    const unsigned int* __restrict__ sortedSrc, float* __restrict__ h,
    int nNodes) {
  const int lane = threadIdx.x & 63;
  const int l15 = lane & 15;
  const int lq  = lane >> 4;

  bf16x8 Wf[8];
  float bv[8];
#pragma unroll
  for (int nt = 0; nt < 8; ++nt) {
#pragma unroll
    for (int j = 0; j < 8; ++j)
      Wf[nt][j] = (short)f2bf(W[(8 * lq + j) * HID + 16 * nt + l15]);
    bv[nt] = bias[16 * nt + l15];
  }

  const int wavesPerBlk = blockDim.x >> 6;
  int waveId = blockIdx.x * wavesPerBlk + ((int)threadIdx.x >> 6);
  const int nWaves = gridDim.x * wavesPerBlk;

  for (int n = waveId; n < nNodes; n += nWaves) {
    const unsigned int beg = offsets[n];
    const unsigned int end = offsets[n + 1];

    float accv[8] = {0, 0, 0, 0, 0, 0, 0, 0};

    for (unsigned int base = beg; base < end; base += 16) {
      // ---- A fragment (16 edges x K32) ----
      bf16x8 af = {0, 0, 0, 0, 0, 0, 0, 0};
      const unsigned int slotA = base + (unsigned int)l15;
      if (slotA < end) {
        if (MODE == 2) {
          const unsigned int eidA = __builtin_nontemporal_load(&sortedEid[slotA]);
          const float* ap = ea + (size_t)eidA * EDIM + 8 * lq;
          f4_t a0 = *(const f4_t*)ap;
          f4_t a1 = *(const f4_t*)(ap + 4);
#pragma unroll
          for (int j = 0; j < 4; ++j) { af[j] = (short)f2bf(a0[j]); af[j + 4] = (short)f2bf(a1[j]); }
        } else {
          af = __builtin_nontemporal_load(
              (const bf16x8*)(eaSorted + (size_t)slotA * EDIM + lq * 8));
        }
      }

      // ---- srcs + x gathers issued before MFMA ----
      unsigned int s_r[4];
      bf16x8 xg[4];
#pragma unroll
      for (int r = 0; r < 4; ++r) {
        unsigned int slot = base + (unsigned int)(lq * 4 + r);
        unsigned int cl = slot < end ? slot : end - 1;
        s_r[r] = sortedSrc[cl];
        if (MODE == 0)
          xg[r] = *(const bf16x8*)(xPerm + (size_t)s_r[r] * HID + l15 * 8);
      }

      f4_t acc[8];
#pragma unroll
      for (int nt = 0; nt < 8; ++nt) {
        f4_t c; c[0] = bv[nt]; c[1] = bv[nt]; c[2] = bv[nt]; c[3] = bv[nt];
        acc[nt] = __builtin_amdgcn_mfma_f32_16x16x32_bf16(af, Wf[nt], c, 0, 0, 0);
      }

#pragma unroll
      for (int r = 0; r < 4; ++r) {
        const unsigned int slot = base + (unsigned int)(lq * 4 + r);
        if (slot < end) {
          if (MODE == 0) {
#pragma unroll
            for (int nt = 0; nt < 8; ++nt)
              accv[nt] += fmaxf(acc[nt][r] + bf2f(xg[r][nt]), 0.f);
          } else {
            const float* xp = x + (size_t)s_r[r] * HID + l15;
#pragma unroll
            for (int nt = 0; nt < 8; ++nt)
              accv[nt] += fmaxf(acc[nt][r] + xp[nt * 16], 0.f);
          }
        }
      }
    }

#pragma unroll
    for (int nt = 0; nt < 8; ++nt) {
      accv[nt] += __shfl_xor(accv[nt], 16);
      accv[nt] += __shfl_xor(accv[nt], 32);
    }

    const int c0 = 32 * lq + l15;
    const size_t rowOff = (size_t)n * HID;
    h[rowOff + c0]      = accv[2 * lq]     + x[rowOff + c0];
    h[rowOff + c0 + 16] = accv[2 * lq + 1] + x[rowOff + c0 + 16];
  }
}

// ---------------------------------------------------------------------------
// Node pass (in place on d_out): h1 = relu(h@W1+b1) ; h2 = h1@W2+b2
// plus per-column sum / sumsq accumulation for GraphNorm.
// ---------------------------------------------------------------------------
__global__ __launch_bounds__(256) void node_kernel(
    float* __restrict__ h, const float* __restrict__ W1, const float* __restrict__ b1,
    const float* __restrict__ W2, const float* __restrict__ b2,
    float* __restrict__ stats, int nNodes, int nTiles) {
  __shared__ unsigned short sW1[128 * 128];
  __shared__ unsigned short sW2[128 * 128];
  __shared__ unsigned short sH1[4][16 * 128];

  for (int idx = threadIdx.x; idx < 128 * 128; idx += 256) {
    int n = idx & 127, k = idx >> 7;
    int off = n * 128 + ((((k >> 3) ^ (n & 15))) << 3) + (k & 7);
    sW1[off] = f2bf(W1[k * HID + n]);
    sW2[off] = f2bf(W2[k * HID + n]);
  }
  __syncthreads();

  const int lane = threadIdx.x & 63;
  const int l15 = lane & 15, lq = lane >> 4;
  const int wv = threadIdx.x >> 6;
  unsigned short* hb = &sH1[wv][0];

  float b1v[8], b2v[8];
#pragma unroll
  for (int nt = 0; nt < 8; ++nt) { b1v[nt] = b1[nt * 16 + l15]; b2v[nt] = b2[nt * 16 + l15]; }
  float ssum[8] = {0, 0, 0, 0, 0, 0, 0, 0};
  float ssq[8]  = {0, 0, 0, 0, 0, 0, 0, 0};

  int waveId = blockIdx.x * 4 + wv;
  const int nWaves = gridDim.x * 4;

  for (int tile = waveId; tile < nTiles; tile += nWaves) {
    const int r0 = tile << 4;
    int rr = r0 + l15; if (rr >= nNodes) rr = nNodes - 1;
    const float* hp = h + (size_t)rr * HID;

    bf16x8 af[4];
#pragma unroll
    for (int kt = 0; kt < 4; ++kt) {
      const int k0 = kt * 32 + 8 * lq;
      f4_t u0 = *(const f4_t*)(hp + k0);
      f4_t u1 = *(const f4_t*)(hp + k0 + 4);
#pragma unroll
      for (int j = 0; j < 4; ++j) {
        af[kt][j]     = (short)f2bf(u0[j]);
        af[kt][j + 4] = (short)f2bf(u1[j]);
      }
    }

    f4_t acc[8];
#pragma unroll
    for (int nt = 0; nt < 8; ++nt) {
      f4_t c; c[0] = b1v[nt]; c[1] = b1v[nt]; c[2] = b1v[nt]; c[3] = b1v[nt];
#pragma unroll
      for (int kt = 0; kt < 4; ++kt) {
        bf16x8 wf = *(const bf16x8*)&sW1[(nt * 16 + l15) * 128 + ((((kt * 4 + lq) ^ l15)) << 3)];
        c = __builtin_amdgcn_mfma_f32_16x16x32_bf16(af[kt], wf, c, 0, 0, 0);
      }
      acc[nt] = c;
    }

#pragma unroll
    for (int nt = 0; nt < 8; ++nt) {
      const int ghi = 2 * nt + (l15 >> 3);
#pragma unroll
      for (int r = 0; r < 4; ++r) {
        const int row = lq * 4 + r;
        hb[row * 128 + ((ghi ^ (row & 15)) << 3) + (l15 & 7)] = f2bf(fmaxf(acc[nt][r], 0.f));
      }
    }
    asm volatile("s_waitcnt lgkmcnt(0)" ::: "memory");
    __builtin_amdgcn_sched_barrier(0);

    bf16x8 af2[4];
#pragma unroll
    for (int kt = 0; kt < 4; ++kt)
      af2[kt] = *(const bf16x8*)&hb[l15 * 128 + ((((kt * 4 + lq) ^ l15)) << 3)];

    f4_t acc2[8];
#pragma unroll
    for (int nt = 0; nt < 8; ++nt) {
      f4_t c; c[0] = b2v[nt]; c[1] = b2v[nt]; c[2] = b2v[nt]; c[3] = b2v[nt];
#pragma unroll
      for (int kt = 0; kt < 4; ++kt) {
        bf16x8 wf = *(const bf16x8*)&sW2[(nt * 16 + l15) * 128 + ((((kt * 4 + lq) ^ l15)) << 3)];
        c = __builtin_amdgcn_mfma_f32_16x16x32_bf16(af2[kt], wf, c, 0, 0, 0);
      }
      acc2[nt] = c;
    }

#pragma unroll
    for (int nt = 0; nt < 8; ++nt) {
#pragma unroll
      for (int r = 0; r < 4; ++r) {
        const int row = r0 + lq * 4 + r;
        if (row < nNodes) {
          float v = acc2[nt][r];
          h[(size_t)row * HID + nt * 16 + l15] = v;
          ssum[nt] += v; ssq[nt] += v * v;
        }
      }
    }
  }

#pragma unroll
  for (int nt = 0; nt < 8; ++nt) {
    float a = ssum[nt], b = ssq[nt];
    a += __shfl_xor(a, 16); b += __shfl_xor(b, 16);
    a += __shfl_xor(a, 32); b += __shfl_xor(b, 32);
    if (lq == 0) {
      atomAddF(&stats[nt * 16 + l15], a);
      atomAddF(&stats[HID + nt * 16 + l15], b);
    }
  }
}

__global__ void norm_prep(float* __restrict__ stats, const float* __restrict__ gw,
                          const float* __restrict__ gb, const float* __restrict__ gs,
                          int nNodes) {
  int c = threadIdx.x;
  if (c < HID) {
    float invN = 1.f / (float)nNodes;
    float m   = stats[c] * invN;
    float msq = stats[HID + c] * invN;
    float s   = gs[c];
    float var = msq - (2.f * s - s * s) * m * m;
    float A = gw[c] * rsqrtf(var + 1e-5f);
    float B = gb[c] - A * s * m;
    stats[2 * HID + c] = A;
    stats[3 * HID + c] = B;
  }
}

__global__ __launch_bounds__(256) void norm_kernel(const float* __restrict__ stats,
                                                   float* __restrict__ out, int total4) {
  const f4_t* A4 = (const f4_t*)(stats + 2 * HID);
  const f4_t* B4 = (const f4_t*)(stats + 3 * HID);
  int i = blockIdx.x * blockDim.x + threadIdx.x;
  const int stride = gridDim.x * blockDim.x;
  for (; i < total4; i += stride) {
    const int cg = i & 31;
    f4_t h = ((const f4_t*)out)[i];
    f4_t a = A4[cg], b = B4[cg];
    f4_t o;
#pragma unroll
    for (int j = 0; j < 4; ++j) o[j] = fmaxf(fmaf(h[j], a[j], b[j]), 0.f);
    ((f4_t*)out)[i] = o;
  }
}

extern "C" void kernel_launch(void* const* d_in, const int* in_sizes, int n_in,
                              void* d_out, int out_size, void* d_ws, size_t ws_size,
                              hipStream_t stream) {
  const float* x  = (const float*)d_in[0];
  const int*   ei = (const int*)d_in[1];
  const float* ea = (const float*)d_in[2];
  const float* eW = (const float*)d_in[3];
  const float* eb = (const float*)d_in[4];
  const float* W1 = (const float*)d_in[5];
  const float* b1 = (const float*)d_in[6];
  const float* W2 = (const float*)d_in[7];
  const float* b2 = (const float*)d_in[8];
  const float* gw = (const float*)d_in[9];
  const float* gb = (const float*)d_in[10];
  const float* gs = (const float*)d_in[11];
  float* out = (float*)d_out;

  const int nNodes = in_sizes[0] / HID;   // 100000
  const int nE     = in_sizes[1] / 2;     // 1600000

  // ws layout
  char* w = (char*)d_ws;
  const size_t offStats   = 0;                                // 4*HID f32
  const size_t offCounts  = 2048;                             // nNodes u32
  const size_t offCursors = offCounts  + (size_t)nNodes * 4;
  const size_t offOffsets = offCursors + (size_t)nNodes * 4;
  const size_t offChunk   = offOffsets + (size_t)(nNodes + 16) * 4;
  const size_t offSSrc    = offChunk   + 2048;                // nE u32
  const size_t base0      = offSSrc    + (size_t)nE * 4;
  // mode 0/1: eaSorted (nE*EDIM bf16) [+ xPerm (nNodes*HID bf16)]
  // mode 2:   sortedEid (nE u32)
  const size_t needB = base0 + (size_t)nE * EDIM * 2;
  const size_t needA = needB + (size_t)nNodes * HID * 2;

  float* stats            = (float*)(w + offStats);
  unsigned int* counts    = (unsigned int*)(w + offCounts);
  unsigned int* cursors   = (unsigned int*)(w + offCursors);
  unsigned int* offsets   = (unsigned int*)(w + offOffsets);
  unsigned int* chunkSum  = (unsigned int*)(w + offChunk);
  unsigned int* chunkOff  = (unsigned int*)(w + offChunk + 1024);
  unsigned int* sortedSrc = (unsigned int*)(w + offSSrc);
  unsigned int* sortedEid = (unsigned int*)(w + base0);
  unsigned short* eaSorted= (unsigned short*)(w + base0);
  unsigned short* xPerm   = (unsigned short*)(w + needB);

  const int mode = (ws_size >= needA) ? 0 : (ws_size >= needB ? 1 : 2);

  hipMemsetAsync(d_ws, 0, offCursors, stream);  // stats + counts

  hist_xperm<<<2048, 256, 0, stream>>>(ei, x, counts, xPerm, nE, nNodes, mode == 0 ? 1 : 0);

  const int nChunks = (nNodes + 1023) / 1024;
  chunk_sum<<<nChunks, 1024, 0, stream>>>(counts, chunkSum, nNodes);
  scan_chunks<<<1, 256, 0, stream>>>(chunkSum, chunkOff, offsets, nChunks, nNodes);
  scan_local<<<nChunks, 1024, 0, stream>>>(counts, chunkOff, offsets, cursors, nNodes);

  if (mode == 2)
    scatter_min<<<1024, 256, 0, stream>>>(ei, cursors, sortedEid, sortedSrc, nE);
  else
    scatter_conv<<<2048, 256, 0, stream>>>(ei, ea, cursors, sortedSrc, eaSorted, nE);

  if (mode == 0)
    agg_kernel<0><<<8192, 256, 0, stream>>>(x, xPerm, ea, eaSorted, eW, eb, offsets, sortedEid, sortedSrc, out, nNodes);
  else if (mode == 1)
    agg_kernel<1><<<8192, 256, 0, stream>>>(x, xPerm, ea, eaSorted, eW, eb, offsets, sortedEid, sortedSrc, out, nNodes);
  else
    agg_kernel<2><<<8192, 256, 0, stream>>>(x, xPerm, ea, eaSorted, eW, eb, offsets, sortedEid, sortedSrc, out, nNodes);

  const int nTiles = (nNodes + 15) >> 4;
  node_kernel<<<782, 256, 0, stream>>>(out, W1, b1, W2, b2, stats, nNodes, nTiles);

  norm_prep<<<1, 128, 0, stream>>>(stats, gw, gb, gs, nNodes);
  norm_kernel<<<2048, 256, 0, stream>>>(stats, out, nNodes * (HID / 4));
}